// Round 17
// baseline (389.997 us; speedup 1.0000x reference)
//
#include <hip/hip_runtime.h>

#define NN 50000
#define NE 800000
#define DD 128

typedef __attribute__((ext_vector_type(8))) short short8;
typedef __attribute__((ext_vector_type(4))) float f32x4;

__device__ inline unsigned short f2bf_rne(float f) {
  unsigned u = __float_as_uint(f);
  u += 0x7FFF + ((u >> 16) & 1);
  return (unsigned short)(u >> 16);
}
__device__ inline float bf2f(unsigned short h) {
  return __uint_as_float(((unsigned)h) << 16);
}
__device__ inline float bflo(unsigned u) { return __uint_as_float(u << 16); }
__device__ inline float bfhi(unsigned u) { return __uint_as_float(u & 0xffff0000u); }

// ------------------------------------------------- fused prologue
__global__ __launch_bounds__(256) void prologue(
    const float* __restrict__ Wl1, const float* __restrict__ Wl2,
    const float* __restrict__ Wp1,
    unsigned short* __restrict__ WTh, unsigned short* __restrict__ WTl,
    const float2* __restrict__ xin2, unsigned* __restrict__ xbf2,
    int* __restrict__ cnt) {
  const int tid = blockIdx.x * 256 + threadIdx.x;
  if (tid < NN) cnt[tid] = 0;
  if (tid < 8 * 16384) {
    const int g = tid >> 14, idx = tid & 16383;
    const int n = idx >> 7, k = idx & 127;
    const float* s;
    if (g < 3) s = Wl1 + (size_t)g * 16384;
    else if (g < 6) s = Wl2 + (size_t)(g - 3) * 16384;
    else s = Wp1 + (size_t)(g - 6) * 16384;
    const float v = s[k * 128 + n];
    const unsigned short hi = f2bf_rne(v);
    WTh[tid] = hi;
    WTl[tid] = f2bf_rne(v - bf2f(hi));
  }
  if (tid < NN * DD / 2) {
    const float2 v = xin2[tid];
    xbf2[tid] = (unsigned)f2bf_rne(v.x) | ((unsigned)f2bf_rne(v.y) << 16);
  }
}

// ------------------------------------------------- CSR build: histogram + rank
__global__ __launch_bounds__(256) void hist_rank(const int* __restrict__ dst,
                                                 int* __restrict__ cnt,
                                                 int* __restrict__ rank) {
  int e = blockIdx.x * 256 + threadIdx.x;
  if (e < NE) rank[e] = atomicAdd(&cnt[dst[e]], 1);
}

// ------------------------------------------------- CSR build: scan (1 block)
__global__ __launch_bounds__(1024) void scan_nodes(const int* __restrict__ cnt,
                                                   int* __restrict__ offs) {
  __shared__ int wsum[16];
  __shared__ int wpre[16];
  const int t = threadIdx.x;
  const int lane = t & 63, wv = t >> 6;
  int carry = 0;
  for (int base = 0; base < NN; base += 8192) {
    const int i0 = base + t * 8;
    int4 a = make_int4(0, 0, 0, 0), b = make_int4(0, 0, 0, 0);
    if (i0 + 8 <= NN) {
      a = *(const int4*)(cnt + i0);
      b = *(const int4*)(cnt + i0 + 4);
    } else if (i0 < NN) {
      int tmp[8];
      for (int j = 0; j < 8; ++j) tmp[j] = (i0 + j < NN) ? cnt[i0 + j] : 0;
      a = make_int4(tmp[0], tmp[1], tmp[2], tmp[3]);
      b = make_int4(tmp[4], tmp[5], tmp[6], tmp[7]);
    }
    const int own = a.x + a.y + a.z + a.w + b.x + b.y + b.z + b.w;
    int inc = own;
#pragma unroll
    for (int d = 1; d < 64; d <<= 1) {
      int v = __shfl_up(inc, d, 64);
      if (lane >= d) inc += v;
    }
    if (lane == 63) wsum[wv] = inc;
    __syncthreads();
    if (t < 16) {
      int v = wsum[t];
      int p = v;
#pragma unroll
      for (int d = 1; d < 16; d <<= 1) {
        int u = __shfl_up(p, d, 16);
        if (t >= d) p += u;
      }
      wpre[t] = p - v;
      if (t == 15) wsum[15] = p;
    }
    __syncthreads();
    int run = carry + wpre[wv] + inc - own;
    const int o0 = run,      o1 = o0 + a.x, o2 = o1 + a.y, o3 = o2 + a.z;
    const int o4 = o3 + a.w, o5 = o4 + b.x, o6 = o5 + b.y, o7 = o6 + b.z;
    if (i0 + 8 <= NN) {
      *(int4*)(offs + i0)     = make_int4(o0, o1, o2, o3);
      *(int4*)(offs + i0 + 4) = make_int4(o4, o5, o6, o7);
    } else if (i0 < NN) {
      const int o[8] = {o0, o1, o2, o3, o4, o5, o6, o7};
      for (int j = 0; j < 8; ++j)
        if (i0 + j < NN) offs[i0 + j] = o[j];
    }
    carry += wsum[15];
    __syncthreads();
  }
  if (t == 0) offs[NN] = carry;
}

// ------------------------------------------------- CSR build: fill (8B packed recs)
// lo = src | (eid_lo16 << 16); hi = eid_hi4 | (ea_bf16 << 16)
__global__ __launch_bounds__(256) void csr_fill(
    const int* __restrict__ src, const int* __restrict__ dst,
    const float* __restrict__ ea, const int* __restrict__ offs,
    const int* __restrict__ rank, uint2* __restrict__ recs) {
  int e = blockIdx.x * 256 + threadIdx.x;
  if (e >= NE) return;
  int pos = offs[dst[e]] + rank[e];
  const unsigned s = (unsigned)src[e];
  const unsigned eb = (unsigned)f2bf_rne(ea[e]);
  recs[pos] = make_uint2(s | ((unsigned)e << 16),
                         ((unsigned)e >> 16) | (eb << 16));
}

// ------------------------------------------------- per-node aggregation
// 16 lanes/node x 8 elems/lane (uint4 gathers); 8-deep unroll.
__global__ __launch_bounds__(256) void aggregate(
    const unsigned short* __restrict__ xbf,
    const int* __restrict__ offs, const uint2* __restrict__ recs,
    const float4* __restrict__ We4, const float4* __restrict__ be4,
    float* __restrict__ out) {
  const int slot = threadIdx.x >> 4, lane = threadIdx.x & 15;
  const int n = blockIdx.x * 16 + slot;
  if (n >= NN) return;
  const float4 wv0 = We4[lane * 2], wv1 = We4[lane * 2 + 1];
  const float4 bv0 = be4[lane * 2], bv1 = be4[lane * 2 + 1];
  float acc[8];
  {
    const uint4 sq = *(const uint4*)(xbf + (size_t)n * DD + lane * 8);
    acc[0] = bflo(sq.x); acc[1] = bfhi(sq.x);
    acc[2] = bflo(sq.y); acc[3] = bfhi(sq.y);
    acc[4] = bflo(sq.z); acc[5] = bfhi(sq.z);
    acc[6] = bflo(sq.w); acc[7] = bfhi(sq.w);
  }
  const int beg = offs[n], end = offs[n + 1];
  int i = beg;
#define ACC8(rec, q)                                                          \
  {                                                                           \
    const float ee = bf2f((unsigned short)((rec).y >> 16));                   \
    acc[0] += fmaxf(fmaf(ee, wv0.x, bv0.x) + bflo((q).x), 0.f);               \
    acc[1] += fmaxf(fmaf(ee, wv0.y, bv0.y) + bfhi((q).x), 0.f);               \
    acc[2] += fmaxf(fmaf(ee, wv0.z, bv0.z) + bflo((q).y), 0.f);               \
    acc[3] += fmaxf(fmaf(ee, wv0.w, bv0.w) + bfhi((q).y), 0.f);               \
    acc[4] += fmaxf(fmaf(ee, wv1.x, bv1.x) + bflo((q).z), 0.f);               \
    acc[5] += fmaxf(fmaf(ee, wv1.y, bv1.y) + bfhi((q).z), 0.f);               \
    acc[6] += fmaxf(fmaf(ee, wv1.z, bv1.z) + bflo((q).w), 0.f);               \
    acc[7] += fmaxf(fmaf(ee, wv1.w, bv1.w) + bfhi((q).w), 0.f);               \
  }
  for (; i + 8 <= end; i += 8) {
    uint2 r[8];
#pragma unroll
    for (int u = 0; u < 8; ++u) r[u] = recs[i + u];
    uint4 q[8];
#pragma unroll
    for (int u = 0; u < 8; ++u)
      q[u] = *(const uint4*)(xbf + (size_t)(r[u].x & 0xFFFFu) * DD + lane * 8);
#pragma unroll
    for (int u = 0; u < 8; ++u) ACC8(r[u], q[u])
  }
  for (; i + 4 <= end; i += 4) {
    uint2 r[4];
#pragma unroll
    for (int u = 0; u < 4; ++u) r[u] = recs[i + u];
    uint4 q[4];
#pragma unroll
    for (int u = 0; u < 4; ++u)
      q[u] = *(const uint4*)(xbf + (size_t)(r[u].x & 0xFFFFu) * DD + lane * 8);
#pragma unroll
    for (int u = 0; u < 4; ++u) ACC8(r[u], q[u])
  }
  for (; i < end; ++i) {
    const uint2 r0 = recs[i];
    const uint4 q0 = *(const uint4*)(xbf + (size_t)(r0.x & 0xFFFFu) * DD + lane * 8);
    ACC8(r0, q0)
  }
#undef ACC8
  float* orow = out + (size_t)n * DD + lane * 8;
  *(float4*)orow = make_float4(acc[0], acc[1], acc[2], acc[3]);
  *(float4*)(orow + 4) = make_float4(acc[4], acc[5], acc[6], acc[7]);
}

// ------------------------------------------------- fused layer MLP (B1+B2 in regs)
template <bool F32OUT, bool BFOUT>
__global__ __launch_bounds__(256) void fused_mlp(
    const float* __restrict__ in,
    const unsigned short* __restrict__ W1h, const unsigned short* __restrict__ W1l,
    const unsigned short* __restrict__ W2h, const unsigned short* __restrict__ W2l,
    const float* __restrict__ b1, const float* __restrict__ b2,
    float* __restrict__ out, unsigned short* __restrict__ outbf) {
  __shared__ float hl[16][132];
  const int t = threadIdx.x;
  const int w = t >> 6, l = t & 63;
  const int lr = l & 15, kg = l >> 4;

  short8 B1h_[2][4], B1l_[2][4], B2h_[2][4], B2l_[2][4];
#pragma unroll
  for (int ct = 0; ct < 2; ++ct)
#pragma unroll
    for (int ks = 0; ks < 4; ++ks) {
      const size_t bo = (size_t)((w * 2 + ct) * 16 + lr) * DD + ks * 32 + kg * 8;
      B1h_[ct][ks] = *(const short8*)(W1h + bo);
      B1l_[ct][ks] = *(const short8*)(W1l + bo);
      B2h_[ct][ks] = *(const short8*)(W2h + bo);
      B2l_[ct][ks] = *(const short8*)(W2l + bo);
    }
  const float b1v0 = b1[(w * 2 + 0) * 16 + lr];
  const float b1v1 = b1[(w * 2 + 1) * 16 + lr];
  const float b2v0 = b2[(w * 2 + 0) * 16 + lr];
  const float b2v1 = b2[(w * 2 + 1) * 16 + lr];

  for (int c = blockIdx.x; c < NN / 16; c += gridDim.x) {
    f32x4 acc[2];
    // ---- GEMM1: A from global f32
    {
      const float* ap = in + ((size_t)c * 16 + lr) * DD + kg * 8;
      float va[4][8];
#pragma unroll
      for (int ks = 0; ks < 4; ++ks) {
        *(float4*)&va[ks][0] = *(const float4*)(ap + ks * 32);
        *(float4*)&va[ks][4] = *(const float4*)(ap + ks * 32 + 4);
      }
      short8 ah[4], al[4];
#pragma unroll
      for (int ks = 0; ks < 4; ++ks)
#pragma unroll
        for (int j = 0; j < 8; ++j) {
          unsigned short h = f2bf_rne(va[ks][j]);
          ah[ks][j] = (short)h;
          al[ks][j] = (short)f2bf_rne(va[ks][j] - bf2f(h));
        }
      acc[0] = (f32x4){0.f, 0.f, 0.f, 0.f};
      acc[1] = (f32x4){0.f, 0.f, 0.f, 0.f};
#pragma unroll
      for (int ks = 0; ks < 4; ++ks)
#pragma unroll
        for (int ct = 0; ct < 2; ++ct) {
          acc[ct] = __builtin_amdgcn_mfma_f32_16x16x32_bf16(ah[ks], B1h_[ct][ks], acc[ct], 0, 0, 0);
          acc[ct] = __builtin_amdgcn_mfma_f32_16x16x32_bf16(ah[ks], B1l_[ct][ks], acc[ct], 0, 0, 0);
          acc[ct] = __builtin_amdgcn_mfma_f32_16x16x32_bf16(al[ks], B1h_[ct][ks], acc[ct], 0, 0, 0);
        }
    }
    // ---- h -> LDS
    __syncthreads();
#pragma unroll
    for (int ct = 0; ct < 2; ++ct) {
      const float bb = ct ? b1v1 : b1v0;
      const int col = (w * 2 + ct) * 16 + lr;
#pragma unroll
      for (int q = 0; q < 4; ++q)
        hl[kg * 4 + q][col] = fmaxf(acc[ct][q] + bb, 0.f);
    }
    __syncthreads();
    // ---- GEMM2: A from LDS
    {
      float va[4][8];
#pragma unroll
      for (int ks = 0; ks < 4; ++ks) {
        *(float4*)&va[ks][0] = *(const float4*)&hl[lr][ks * 32 + kg * 8];
        *(float4*)&va[ks][4] = *(const float4*)&hl[lr][ks * 32 + kg * 8 + 4];
      }
      short8 ah[4], al[4];
#pragma unroll
      for (int ks = 0; ks < 4; ++ks)
#pragma unroll
        for (int j = 0; j < 8; ++j) {
          unsigned short h = f2bf_rne(va[ks][j]);
          ah[ks][j] = (short)h;
          al[ks][j] = (short)f2bf_rne(va[ks][j] - bf2f(h));
        }
      acc[0] = (f32x4){0.f, 0.f, 0.f, 0.f};
      acc[1] = (f32x4){0.f, 0.f, 0.f, 0.f};
#pragma unroll
      for (int ks = 0; ks < 4; ++ks)
#pragma unroll
        for (int ct = 0; ct < 2; ++ct) {
          acc[ct] = __builtin_amdgcn_mfma_f32_16x16x32_bf16(ah[ks], B2h_[ct][ks], acc[ct], 0, 0, 0);
          acc[ct] = __builtin_amdgcn_mfma_f32_16x16x32_bf16(ah[ks], B2l_[ct][ks], acc[ct], 0, 0, 0);
          acc[ct] = __builtin_amdgcn_mfma_f32_16x16x32_bf16(al[ks], B2h_[ct][ks], acc[ct], 0, 0, 0);
        }
    }
    // ---- epilogue
#pragma unroll
    for (int ct = 0; ct < 2; ++ct) {
      const float bb = ct ? b2v1 : b2v0;
      const int col = (w * 2 + ct) * 16 + lr;
#pragma unroll
      for (int q = 0; q < 4; ++q) {
        const float v = fmaxf(acc[ct][q] + bb, 0.f);
        const size_t r = (size_t)c * 16 + kg * 4 + q;
        if (F32OUT) out[r * DD + col] = v;
        if (BFOUT) outbf[r * DD + col] = f2bf_rne(v);
      }
    }
  }
}

// ------------------------------------------------- fused predictor GEMMs
__global__ __launch_bounds__(256) void gemm_pred2(
    const float* __restrict__ in,
    const unsigned short* __restrict__ W1h, const unsigned short* __restrict__ W1l,
    const unsigned short* __restrict__ W2h, const unsigned short* __restrict__ W2l,
    const float* __restrict__ bp1,
    unsigned short* __restrict__ P1bf, unsigned short* __restrict__ P2bf) {
  const int t = threadIdx.x;
  const int w = t >> 6, l = t & 63;
  const int lr = l & 15, kg = l >> 4;

  short8 B1h[2][4], B1l[2][4], B2h[2][4], B2l[2][4];
#pragma unroll
  for (int ct = 0; ct < 2; ++ct)
#pragma unroll
    for (int ks = 0; ks < 4; ++ks) {
      const size_t bo = (size_t)((w * 2 + ct) * 16 + lr) * DD + ks * 32 + kg * 8;
      B1h[ct][ks] = *(const short8*)(W1h + bo);
      B1l[ct][ks] = *(const short8*)(W1l + bo);
      B2h[ct][ks] = *(const short8*)(W2h + bo);
      B2l[ct][ks] = *(const short8*)(W2l + bo);
    }
  float bv0 = bp1[(w * 2 + 0) * 16 + lr];
  float bv1 = bp1[(w * 2 + 1) * 16 + lr];

  for (int c = blockIdx.x; c < NN / 16; c += gridDim.x) {
    const float* ap = in + ((size_t)c * 16 + lr) * DD + kg * 8;
    float va[4][8];
#pragma unroll
    for (int ks = 0; ks < 4; ++ks) {
      *(float4*)&va[ks][0] = *(const float4*)(ap + ks * 32);
      *(float4*)&va[ks][4] = *(const float4*)(ap + ks * 32 + 4);
    }
    short8 ah[4], al[4];
#pragma unroll
    for (int ks = 0; ks < 4; ++ks)
#pragma unroll
      for (int j = 0; j < 8; ++j) {
        unsigned short h = f2bf_rne(va[ks][j]);
        ah[ks][j] = (short)h;
        al[ks][j] = (short)f2bf_rne(va[ks][j] - bf2f(h));
      }
    f32x4 acc1[2], acc2[2];
    acc1[0] = (f32x4){0.f, 0.f, 0.f, 0.f};
    acc1[1] = (f32x4){0.f, 0.f, 0.f, 0.f};
    acc2[0] = (f32x4){0.f, 0.f, 0.f, 0.f};
    acc2[1] = (f32x4){0.f, 0.f, 0.f, 0.f};
#pragma unroll
    for (int ks = 0; ks < 4; ++ks) {
#pragma unroll
      for (int ct = 0; ct < 2; ++ct) {
        acc1[ct] = __builtin_amdgcn_mfma_f32_16x16x32_bf16(ah[ks], B1h[ct][ks], acc1[ct], 0, 0, 0);
        acc1[ct] = __builtin_amdgcn_mfma_f32_16x16x32_bf16(ah[ks], B1l[ct][ks], acc1[ct], 0, 0, 0);
        acc1[ct] = __builtin_amdgcn_mfma_f32_16x16x32_bf16(al[ks], B1h[ct][ks], acc1[ct], 0, 0, 0);
        acc2[ct] = __builtin_amdgcn_mfma_f32_16x16x32_bf16(ah[ks], B2h[ct][ks], acc2[ct], 0, 0, 0);
        acc2[ct] = __builtin_amdgcn_mfma_f32_16x16x32_bf16(ah[ks], B2l[ct][ks], acc2[ct], 0, 0, 0);
        acc2[ct] = __builtin_amdgcn_mfma_f32_16x16x32_bf16(al[ks], B2h[ct][ks], acc2[ct], 0, 0, 0);
      }
    }
#pragma unroll
    for (int ct = 0; ct < 2; ++ct) {
      const int col = (w * 2 + ct) * 16 + lr;
      const float bb = ct ? bv1 : bv0;
#pragma unroll
      for (int q4 = 0; q4 < 4; ++q4) {
        const size_t r = (size_t)c * 16 + kg * 4 + q4;
        P1bf[r * DD + col] = f2bf_rne(acc1[ct][q4]);
        P2bf[r * DD + col] = f2bf_rne(acc2[ct][q4] + bb);
      }
    }
  }
}

// ------------------------------------------------- final edge pass
// 16 lanes/node x 8 elems/lane; 4-stage reduce; 8-deep unroll.
__global__ __launch_bounds__(256) void edge_out(
    const unsigned short* __restrict__ P1bf, const unsigned short* __restrict__ P2bf,
    const int* __restrict__ offs, const uint2* __restrict__ recs,
    const float4* __restrict__ Wp2_4,
    const float* __restrict__ bp2, float* __restrict__ out) {
  const int slot = threadIdx.x >> 4, lane = threadIdx.x & 15;
  const int n = blockIdx.x * 16 + slot;
  if (n >= NN) return;
  const float4 w0 = Wp2_4[lane * 2], w1 = Wp2_4[lane * 2 + 1];
  const float bb = bp2[0];
  float p[8];
  {
    const uint4 pq = *(const uint4*)(P2bf + (size_t)n * DD + lane * 8);
    p[0] = bflo(pq.x); p[1] = bfhi(pq.x);
    p[2] = bflo(pq.y); p[3] = bfhi(pq.y);
    p[4] = bflo(pq.z); p[5] = bfhi(pq.z);
    p[6] = bflo(pq.w); p[7] = bfhi(pq.w);
  }
  const int beg = offs[n], end = offs[n + 1];
  int i = beg;
#define EDGEV(vv, q)                                                          \
  {                                                                           \
    vv = fmaxf(bflo((q).x) + p[0], 0.f) * w0.x                                \
       + fmaxf(bfhi((q).x) + p[1], 0.f) * w0.y                                \
       + fmaxf(bflo((q).y) + p[2], 0.f) * w0.z                                \
       + fmaxf(bfhi((q).y) + p[3], 0.f) * w0.w                                \
       + fmaxf(bflo((q).z) + p[4], 0.f) * w1.x                                \
       + fmaxf(bfhi((q).z) + p[5], 0.f) * w1.y                                \
       + fmaxf(bflo((q).w) + p[6], 0.f) * w1.z                                \
       + fmaxf(bfhi((q).w) + p[7], 0.f) * w1.w;                               \
  }
#define EID(r) (((r).x >> 16) | (((r).y & 0xFFFFu) << 16))
  for (; i + 8 <= end; i += 8) {
    uint2 r[8];
#pragma unroll
    for (int u = 0; u < 8; ++u) r[u] = recs[i + u];
    uint4 q[8];
#pragma unroll
    for (int u = 0; u < 8; ++u)
      q[u] = *(const uint4*)(P1bf + (size_t)(r[u].x & 0xFFFFu) * DD + lane * 8);
    float v[8];
#pragma unroll
    for (int u = 0; u < 8; ++u) EDGEV(v[u], q[u])
#pragma unroll
    for (int m = 8; m >= 1; m >>= 1) {
#pragma unroll
      for (int u = 0; u < 8; ++u) v[u] += __shfl_xor(v[u], m, 64);
    }
    if (lane == 0) {
#pragma unroll
      for (int u = 0; u < 8; ++u) out[EID(r[u])] = v[u] + bb;
    }
  }
  for (; i + 4 <= end; i += 4) {
    uint2 r[4];
#pragma unroll
    for (int u = 0; u < 4; ++u) r[u] = recs[i + u];
    uint4 q[4];
#pragma unroll
    for (int u = 0; u < 4; ++u)
      q[u] = *(const uint4*)(P1bf + (size_t)(r[u].x & 0xFFFFu) * DD + lane * 8);
    float v[4];
#pragma unroll
    for (int u = 0; u < 4; ++u) EDGEV(v[u], q[u])
#pragma unroll
    for (int m = 8; m >= 1; m >>= 1) {
#pragma unroll
      for (int u = 0; u < 4; ++u) v[u] += __shfl_xor(v[u], m, 64);
    }
    if (lane == 0) {
#pragma unroll
      for (int u = 0; u < 4; ++u) out[EID(r[u])] = v[u] + bb;
    }
  }
  for (; i < end; ++i) {
    const uint2 r0 = recs[i];
    const uint4 q0 = *(const uint4*)(P1bf + (size_t)(r0.x & 0xFFFFu) * DD + lane * 8);
    float v;
    EDGEV(v, q0)
#pragma unroll
    for (int m = 8; m >= 1; m >>= 1) v += __shfl_xor(v, m, 64);
    if (lane == 0) out[EID(r0)] = v + bb;
  }
#undef EDGEV
#undef EID
}

// ---------------------------------------------------------------- launch
extern "C" void kernel_launch(void* const* d_in, const int* in_sizes, int n_in,
                              void* d_out, int out_size, void* d_ws, size_t ws_size,
                              hipStream_t stream) {
  const float* x_in = (const float*)d_in[0];
  const float* ea   = (const float*)d_in[1];
  const int*   ei   = (const int*)d_in[2];   // integer inputs arrive as int32
  const float* Wl1 = (const float*)d_in[3];
  const float* bl1 = (const float*)d_in[4];
  const float* Wl2 = (const float*)d_in[5];
  const float* bl2 = (const float*)d_in[6];
  const float* We  = (const float*)d_in[7];
  const float* be  = (const float*)d_in[8];
  const float* Wp1 = (const float*)d_in[9];
  const float* bp1 = (const float*)d_in[10];
  const float* Wp2 = (const float*)d_in[11];
  const float* bp2 = (const float*)d_in[12];
  const int* src = ei;
  const int* dst = ei + NE;

  // workspace layout (~75 MB)
  float* bufA   = (float*)d_ws;                    // NN*DD f32
  float* bufB   = bufA + (size_t)NN * DD;          // NN*DD f32
  int*   cnt    = (int*)(bufB + (size_t)NN * DD);  // NN
  int*   offs   = cnt + NN;                        // NN+1
  int*   rank   = offs + NN + 1;                   // NE
  uint2* recs   = (uint2*)(((uintptr_t)(rank + NE) + 15) & ~(uintptr_t)15); // NE x 8B
  unsigned short* WTh = (unsigned short*)(recs + NE);   // 8*16384 bf16
  unsigned short* WTl = WTh + 8 * 16384;                // 8*16384 bf16
  unsigned short* xbf = WTl + 8 * 16384;                // NN*DD bf16 (x_l / P2bf)

  // fused prologue + CSR build (per-launch, deterministic)
  prologue<<<(NN * DD / 2 + 255) / 256, 256, 0, stream>>>(
      Wl1, Wl2, Wp1, WTh, WTl, (const float2*)x_in, (unsigned*)xbf, cnt);
  hist_rank<<<NE / 256, 256, 0, stream>>>(dst, cnt, rank);
  scan_nodes<<<1, 1024, 0, stream>>>(cnt, offs);
  csr_fill<<<NE / 256, 256, 0, stream>>>(src, dst, ea, offs, rank, recs);

  const int GB = 1024;             // gemm grid: ~3 chunks/block
  const int AB = (NN + 15) / 16;   // 3125 blocks: 16-lane slot per node
#define WH(g) (WTh + (size_t)(g) * 16384)
#define WL(g) (WTl + (size_t)(g) * 16384)

  // L0
  aggregate<<<AB, 256, 0, stream>>>(
      xbf, offs, recs, (const float4*)We, (const float4*)be, bufA);
  fused_mlp<false, true><<<GB, 256, 0, stream>>>(
      bufA, WH(0), WL(0), WH(3), WL(3), bl1, bl2, nullptr, xbf);
  // L1
  aggregate<<<AB, 256, 0, stream>>>(
      xbf, offs, recs, (const float4*)(We + DD), (const float4*)(be + DD), bufA);
  fused_mlp<false, true><<<GB, 256, 0, stream>>>(
      bufA, WH(1), WL(1), WH(4), WL(4), bl1 + DD, bl2 + DD, nullptr, xbf);
  // L2
  aggregate<<<AB, 256, 0, stream>>>(
      xbf, offs, recs, (const float4*)(We + 2 * DD), (const float4*)(be + 2 * DD), bufA);
  fused_mlp<true, false><<<GB, 256, 0, stream>>>(
      bufA, WH(2), WL(2), WH(5), WL(5), bl1 + 2 * DD, bl2 + 2 * DD, bufB, nullptr);
  // predictor: xf = bufB.  P1bf -> bufA storage; P2bf -> xbf.
  gemm_pred2<<<GB, 256, 0, stream>>>(bufB, WH(6), WL(6), WH(7), WL(7), bp1,
                                     (unsigned short*)bufA, xbf);
  edge_out<<<AB, 256, 0, stream>>>(
      (const unsigned short*)bufA, xbf, offs, recs,
      (const float4*)Wp2, bp2, (float*)d_out);
}

// Round 18
// 355.641 us; speedup vs baseline: 1.0966x; 1.0966x over previous
//
#include <hip/hip_runtime.h>

#define NN 50000
#define NE 800000
#define DD 128

typedef __attribute__((ext_vector_type(8))) short short8;
typedef __attribute__((ext_vector_type(4))) float f32x4;

__device__ inline unsigned short f2bf_rne(float f) {
  unsigned u = __float_as_uint(f);
  u += 0x7FFF + ((u >> 16) & 1);
  return (unsigned short)(u >> 16);
}
__device__ inline float bf2f(unsigned short h) {
  return __uint_as_float(((unsigned)h) << 16);
}
__device__ inline float bflo(unsigned u) { return __uint_as_float(u << 16); }
__device__ inline float bfhi(unsigned u) { return __uint_as_float(u & 0xffff0000u); }

// ------------------------------------------------- fused prologue
__global__ __launch_bounds__(256) void prologue(
    const float* __restrict__ Wl1, const float* __restrict__ Wl2,
    const float* __restrict__ Wp1,
    unsigned short* __restrict__ WTh, unsigned short* __restrict__ WTl,
    const float2* __restrict__ xin2, unsigned* __restrict__ xbf2,
    int* __restrict__ cnt) {
  const int tid = blockIdx.x * 256 + threadIdx.x;
  if (tid < NN) cnt[tid] = 0;
  if (tid < 8 * 16384) {
    const int g = tid >> 14, idx = tid & 16383;
    const int n = idx >> 7, k = idx & 127;
    const float* s;
    if (g < 3) s = Wl1 + (size_t)g * 16384;
    else if (g < 6) s = Wl2 + (size_t)(g - 3) * 16384;
    else s = Wp1 + (size_t)(g - 6) * 16384;
    const float v = s[k * 128 + n];
    const unsigned short hi = f2bf_rne(v);
    WTh[tid] = hi;
    WTl[tid] = f2bf_rne(v - bf2f(hi));
  }
  if (tid < NN * DD / 2) {
    const float2 v = xin2[tid];
    xbf2[tid] = (unsigned)f2bf_rne(v.x) | ((unsigned)f2bf_rne(v.y) << 16);
  }
}

// ------------------------------------------------- CSR build: histogram + rank
__global__ __launch_bounds__(256) void hist_rank(const int* __restrict__ dst,
                                                 int* __restrict__ cnt,
                                                 int* __restrict__ rank) {
  int e = blockIdx.x * 256 + threadIdx.x;
  if (e < NE) rank[e] = atomicAdd(&cnt[dst[e]], 1);
}

// ------------------------------------------------- CSR build: scan (1 block)
__global__ __launch_bounds__(1024) void scan_nodes(const int* __restrict__ cnt,
                                                   int* __restrict__ offs) {
  __shared__ int wsum[16];
  __shared__ int wpre[16];
  const int t = threadIdx.x;
  const int lane = t & 63, wv = t >> 6;
  int carry = 0;
  for (int base = 0; base < NN; base += 8192) {
    const int i0 = base + t * 8;
    int4 a = make_int4(0, 0, 0, 0), b = make_int4(0, 0, 0, 0);
    if (i0 + 8 <= NN) {
      a = *(const int4*)(cnt + i0);
      b = *(const int4*)(cnt + i0 + 4);
    } else if (i0 < NN) {
      int tmp[8];
      for (int j = 0; j < 8; ++j) tmp[j] = (i0 + j < NN) ? cnt[i0 + j] : 0;
      a = make_int4(tmp[0], tmp[1], tmp[2], tmp[3]);
      b = make_int4(tmp[4], tmp[5], tmp[6], tmp[7]);
    }
    const int own = a.x + a.y + a.z + a.w + b.x + b.y + b.z + b.w;
    int inc = own;
#pragma unroll
    for (int d = 1; d < 64; d <<= 1) {
      int v = __shfl_up(inc, d, 64);
      if (lane >= d) inc += v;
    }
    if (lane == 63) wsum[wv] = inc;
    __syncthreads();
    if (t < 16) {
      int v = wsum[t];
      int p = v;
#pragma unroll
      for (int d = 1; d < 16; d <<= 1) {
        int u = __shfl_up(p, d, 16);
        if (t >= d) p += u;
      }
      wpre[t] = p - v;
      if (t == 15) wsum[15] = p;
    }
    __syncthreads();
    int run = carry + wpre[wv] + inc - own;
    const int o0 = run,      o1 = o0 + a.x, o2 = o1 + a.y, o3 = o2 + a.z;
    const int o4 = o3 + a.w, o5 = o4 + b.x, o6 = o5 + b.y, o7 = o6 + b.z;
    if (i0 + 8 <= NN) {
      *(int4*)(offs + i0)     = make_int4(o0, o1, o2, o3);
      *(int4*)(offs + i0 + 4) = make_int4(o4, o5, o6, o7);
    } else if (i0 < NN) {
      const int o[8] = {o0, o1, o2, o3, o4, o5, o6, o7};
      for (int j = 0; j < 8; ++j)
        if (i0 + j < NN) offs[i0 + j] = o[j];
    }
    carry += wsum[15];
    __syncthreads();
  }
  if (t == 0) offs[NN] = carry;
}

// ------------------------------------------------- CSR build: fill (8B packed recs)
// lo = src | (eid_lo16 << 16); hi = eid_hi4 | (ea_bf16 << 16)
__global__ __launch_bounds__(256) void csr_fill(
    const int* __restrict__ src, const int* __restrict__ dst,
    const float* __restrict__ ea, const int* __restrict__ offs,
    const int* __restrict__ rank, uint2* __restrict__ recs) {
  int e = blockIdx.x * 256 + threadIdx.x;
  if (e >= NE) return;
  int pos = offs[dst[e]] + rank[e];
  const unsigned s = (unsigned)src[e];
  const unsigned eb = (unsigned)f2bf_rne(ea[e]);
  recs[pos] = make_uint2(s | ((unsigned)e << 16),
                         ((unsigned)e >> 16) | (eb << 16));
}

// ------------------------------------------------- per-node aggregation
// 32 lanes/node (6250 blocks, max TLP); bf16 in AND out; 8-deep unroll.
__global__ __launch_bounds__(256) void aggregate(
    const unsigned short* __restrict__ xbf,
    const int* __restrict__ offs, const uint2* __restrict__ recs,
    const float4* __restrict__ We4, const float4* __restrict__ be4,
    unsigned* __restrict__ outbf2) {   // NN*DD/2 packed bf16 pairs
  const int slot = threadIdx.x >> 5, lane = threadIdx.x & 31;
  const int n = blockIdx.x * 8 + slot;
  if (n >= NN) return;
  const float4 wv = We4[lane], bv = be4[lane];
  float4 a0, a1, a2, a3;
  {
    const uint2 sq = *(const uint2*)(xbf + (size_t)n * DD + lane * 4);
    a0.x = bflo(sq.x); a0.y = bfhi(sq.x);
    a0.z = bflo(sq.y); a0.w = bfhi(sq.y);
  }
  a1 = make_float4(0.f, 0.f, 0.f, 0.f);
  a2 = make_float4(0.f, 0.f, 0.f, 0.f);
  a3 = make_float4(0.f, 0.f, 0.f, 0.f);
  const int beg = offs[n], end = offs[n + 1];
  int i = beg;
#define ACCQ(acc, rec, qq)                                                    \
  {                                                                           \
    const float ee = bf2f((unsigned short)((rec).y >> 16));                   \
    acc.x += fmaxf(fmaf(ee, wv.x, bv.x) + bflo((qq).x), 0.f);                 \
    acc.y += fmaxf(fmaf(ee, wv.y, bv.y) + bfhi((qq).x), 0.f);                 \
    acc.z += fmaxf(fmaf(ee, wv.z, bv.z) + bflo((qq).y), 0.f);                 \
    acc.w += fmaxf(fmaf(ee, wv.w, bv.w) + bfhi((qq).y), 0.f);                 \
  }
  for (; i + 8 <= end; i += 8) {
    uint2 r[8];
#pragma unroll
    for (int u = 0; u < 8; ++u) r[u] = recs[i + u];
    uint2 q[8];
#pragma unroll
    for (int u = 0; u < 8; ++u)
      q[u] = *(const uint2*)(xbf + (size_t)(r[u].x & 0xFFFFu) * DD + lane * 4);
    ACCQ(a0, r[0], q[0]) ACCQ(a1, r[1], q[1]) ACCQ(a2, r[2], q[2]) ACCQ(a3, r[3], q[3])
    ACCQ(a0, r[4], q[4]) ACCQ(a1, r[5], q[5]) ACCQ(a2, r[6], q[6]) ACCQ(a3, r[7], q[7])
  }
  for (; i + 4 <= end; i += 4) {
    uint2 r[4];
#pragma unroll
    for (int u = 0; u < 4; ++u) r[u] = recs[i + u];
    uint2 q[4];
#pragma unroll
    for (int u = 0; u < 4; ++u)
      q[u] = *(const uint2*)(xbf + (size_t)(r[u].x & 0xFFFFu) * DD + lane * 4);
    ACCQ(a0, r[0], q[0]) ACCQ(a1, r[1], q[1]) ACCQ(a2, r[2], q[2]) ACCQ(a3, r[3], q[3])
  }
  for (; i < end; ++i) {
    const uint2 r0 = recs[i];
    const uint2 q0 = *(const uint2*)(xbf + (size_t)(r0.x & 0xFFFFu) * DD + lane * 4);
    ACCQ(a0, r0, q0)
  }
#undef ACCQ
  a0.x += a1.x + a2.x + a3.x;
  a0.y += a1.y + a2.y + a3.y;
  a0.z += a1.z + a2.z + a3.z;
  a0.w += a1.w + a2.w + a3.w;
  const unsigned lo = (unsigned)f2bf_rne(a0.x) | ((unsigned)f2bf_rne(a0.y) << 16);
  const unsigned hi = (unsigned)f2bf_rne(a0.z) | ((unsigned)f2bf_rne(a0.w) << 16);
  uint2* orow = (uint2*)(outbf2 + (size_t)n * (DD / 2)) + lane;
  *orow = make_uint2(lo, hi);
}

// ------------------------------------------------- fused layer MLP
// A input bf16 (direct MFMA frags, GEMM1 = 2 MFMA); h f32 via LDS (3 MFMA);
// output bf16.
__global__ __launch_bounds__(256) void fused_mlp(
    const unsigned short* __restrict__ in,
    const unsigned short* __restrict__ W1h, const unsigned short* __restrict__ W1l,
    const unsigned short* __restrict__ W2h, const unsigned short* __restrict__ W2l,
    const float* __restrict__ b1, const float* __restrict__ b2,
    unsigned short* __restrict__ outbf) {
  __shared__ float hl[16][132];
  const int t = threadIdx.x;
  const int w = t >> 6, l = t & 63;
  const int lr = l & 15, kg = l >> 4;

  short8 B1h_[2][4], B1l_[2][4], B2h_[2][4], B2l_[2][4];
#pragma unroll
  for (int ct = 0; ct < 2; ++ct)
#pragma unroll
    for (int ks = 0; ks < 4; ++ks) {
      const size_t bo = (size_t)((w * 2 + ct) * 16 + lr) * DD + ks * 32 + kg * 8;
      B1h_[ct][ks] = *(const short8*)(W1h + bo);
      B1l_[ct][ks] = *(const short8*)(W1l + bo);
      B2h_[ct][ks] = *(const short8*)(W2h + bo);
      B2l_[ct][ks] = *(const short8*)(W2l + bo);
    }
  const float b1v0 = b1[(w * 2 + 0) * 16 + lr];
  const float b1v1 = b1[(w * 2 + 1) * 16 + lr];
  const float b2v0 = b2[(w * 2 + 0) * 16 + lr];
  const float b2v1 = b2[(w * 2 + 1) * 16 + lr];

  for (int c = blockIdx.x; c < NN / 16; c += gridDim.x) {
    f32x4 acc[2];
    // ---- GEMM1: A direct from bf16 (2 MFMA per ct)
    {
      const unsigned short* ap = in + ((size_t)c * 16 + lr) * DD + kg * 8;
      short8 ah[4];
#pragma unroll
      for (int ks = 0; ks < 4; ++ks) ah[ks] = *(const short8*)(ap + ks * 32);
      acc[0] = (f32x4){0.f, 0.f, 0.f, 0.f};
      acc[1] = (f32x4){0.f, 0.f, 0.f, 0.f};
#pragma unroll
      for (int ks = 0; ks < 4; ++ks)
#pragma unroll
        for (int ct = 0; ct < 2; ++ct) {
          acc[ct] = __builtin_amdgcn_mfma_f32_16x16x32_bf16(ah[ks], B1h_[ct][ks], acc[ct], 0, 0, 0);
          acc[ct] = __builtin_amdgcn_mfma_f32_16x16x32_bf16(ah[ks], B1l_[ct][ks], acc[ct], 0, 0, 0);
        }
    }
    // ---- h -> LDS (f32, lossless)
    __syncthreads();
#pragma unroll
    for (int ct = 0; ct < 2; ++ct) {
      const float bb = ct ? b1v1 : b1v0;
      const int col = (w * 2 + ct) * 16 + lr;
#pragma unroll
      for (int q = 0; q < 4; ++q)
        hl[kg * 4 + q][col] = fmaxf(acc[ct][q] + bb, 0.f);
    }
    __syncthreads();
    // ---- GEMM2: A from LDS (hi/lo split, 3 MFMA per ct)
    {
      float va[4][8];
#pragma unroll
      for (int ks = 0; ks < 4; ++ks) {
        *(float4*)&va[ks][0] = *(const float4*)&hl[lr][ks * 32 + kg * 8];
        *(float4*)&va[ks][4] = *(const float4*)&hl[lr][ks * 32 + kg * 8 + 4];
      }
      short8 ah[4], al[4];
#pragma unroll
      for (int ks = 0; ks < 4; ++ks)
#pragma unroll
        for (int j = 0; j < 8; ++j) {
          unsigned short h = f2bf_rne(va[ks][j]);
          ah[ks][j] = (short)h;
          al[ks][j] = (short)f2bf_rne(va[ks][j] - bf2f(h));
        }
      acc[0] = (f32x4){0.f, 0.f, 0.f, 0.f};
      acc[1] = (f32x4){0.f, 0.f, 0.f, 0.f};
#pragma unroll
      for (int ks = 0; ks < 4; ++ks)
#pragma unroll
        for (int ct = 0; ct < 2; ++ct) {
          acc[ct] = __builtin_amdgcn_mfma_f32_16x16x32_bf16(ah[ks], B2h_[ct][ks], acc[ct], 0, 0, 0);
          acc[ct] = __builtin_amdgcn_mfma_f32_16x16x32_bf16(ah[ks], B2l_[ct][ks], acc[ct], 0, 0, 0);
          acc[ct] = __builtin_amdgcn_mfma_f32_16x16x32_bf16(al[ks], B2h_[ct][ks], acc[ct], 0, 0, 0);
        }
    }
    // ---- epilogue (bf16)
#pragma unroll
    for (int ct = 0; ct < 2; ++ct) {
      const float bb = ct ? b2v1 : b2v0;
      const int col = (w * 2 + ct) * 16 + lr;
#pragma unroll
      for (int q = 0; q < 4; ++q) {
        const float v = fmaxf(acc[ct][q] + bb, 0.f);
        outbf[((size_t)c * 16 + kg * 4 + q) * DD + col] = f2bf_rne(v);
      }
    }
  }
}

// ------------------------------------------------- fused predictor GEMMs
// A bf16 direct (2 MFMA per output); P1, P2 both bf16.
__global__ __launch_bounds__(256) void gemm_pred2(
    const unsigned short* __restrict__ in,
    const unsigned short* __restrict__ W1h, const unsigned short* __restrict__ W1l,
    const unsigned short* __restrict__ W2h, const unsigned short* __restrict__ W2l,
    const float* __restrict__ bp1,
    unsigned short* __restrict__ P1bf, unsigned short* __restrict__ P2bf) {
  const int t = threadIdx.x;
  const int w = t >> 6, l = t & 63;
  const int lr = l & 15, kg = l >> 4;

  short8 B1h[2][4], B1l[2][4], B2h[2][4], B2l[2][4];
#pragma unroll
  for (int ct = 0; ct < 2; ++ct)
#pragma unroll
    for (int ks = 0; ks < 4; ++ks) {
      const size_t bo = (size_t)((w * 2 + ct) * 16 + lr) * DD + ks * 32 + kg * 8;
      B1h[ct][ks] = *(const short8*)(W1h + bo);
      B1l[ct][ks] = *(const short8*)(W1l + bo);
      B2h[ct][ks] = *(const short8*)(W2h + bo);
      B2l[ct][ks] = *(const short8*)(W2l + bo);
    }
  float bv0 = bp1[(w * 2 + 0) * 16 + lr];
  float bv1 = bp1[(w * 2 + 1) * 16 + lr];

  for (int c = blockIdx.x; c < NN / 16; c += gridDim.x) {
    const unsigned short* ap = in + ((size_t)c * 16 + lr) * DD + kg * 8;
    short8 ah[4];
#pragma unroll
    for (int ks = 0; ks < 4; ++ks) ah[ks] = *(const short8*)(ap + ks * 32);
    f32x4 acc1[2], acc2[2];
    acc1[0] = (f32x4){0.f, 0.f, 0.f, 0.f};
    acc1[1] = (f32x4){0.f, 0.f, 0.f, 0.f};
    acc2[0] = (f32x4){0.f, 0.f, 0.f, 0.f};
    acc2[1] = (f32x4){0.f, 0.f, 0.f, 0.f};
#pragma unroll
    for (int ks = 0; ks < 4; ++ks) {
#pragma unroll
      for (int ct = 0; ct < 2; ++ct) {
        acc1[ct] = __builtin_amdgcn_mfma_f32_16x16x32_bf16(ah[ks], B1h[ct][ks], acc1[ct], 0, 0, 0);
        acc1[ct] = __builtin_amdgcn_mfma_f32_16x16x32_bf16(ah[ks], B1l[ct][ks], acc1[ct], 0, 0, 0);
        acc2[ct] = __builtin_amdgcn_mfma_f32_16x16x32_bf16(ah[ks], B2h[ct][ks], acc2[ct], 0, 0, 0);
        acc2[ct] = __builtin_amdgcn_mfma_f32_16x16x32_bf16(ah[ks], B2l[ct][ks], acc2[ct], 0, 0, 0);
      }
    }
#pragma unroll
    for (int ct = 0; ct < 2; ++ct) {
      const int col = (w * 2 + ct) * 16 + lr;
      const float bb = ct ? bv1 : bv0;
#pragma unroll
      for (int q4 = 0; q4 < 4; ++q4) {
        const size_t r = (size_t)c * 16 + kg * 4 + q4;
        P1bf[r * DD + col] = f2bf_rne(acc1[ct][q4]);
        P2bf[r * DD + col] = f2bf_rne(acc2[ct][q4] + bb);
      }
    }
  }
}

// ------------------------------------------------- final edge pass
// 32 lanes/node (6250 blocks); P1/P2 bf16; 8-deep unroll.
__global__ __launch_bounds__(256) void edge_out(
    const unsigned short* __restrict__ P1bf, const unsigned short* __restrict__ P2bf,
    const int* __restrict__ offs, const uint2* __restrict__ recs,
    const float4* __restrict__ Wp2_4,
    const float* __restrict__ bp2, float* __restrict__ out) {
  const int slot = threadIdx.x >> 5, lane = threadIdx.x & 31;
  const int n = blockIdx.x * 8 + slot;
  if (n >= NN) return;
  const float4 w = Wp2_4[lane];
  const float bb = bp2[0];
  float4 p2;
  {
    const uint2 pq = *(const uint2*)(P2bf + (size_t)n * DD + lane * 4);
    p2.x = bflo(pq.x); p2.y = bfhi(pq.x);
    p2.z = bflo(pq.y); p2.w = bfhi(pq.y);
  }
  const int beg = offs[n], end = offs[n + 1];
  int i = beg;
#define EDGEV(vv, qq)                                                         \
  {                                                                           \
    vv = fmaxf(bflo((qq).x) + p2.x, 0.f) * w.x                                \
       + fmaxf(bfhi((qq).x) + p2.y, 0.f) * w.y                                \
       + fmaxf(bflo((qq).y) + p2.z, 0.f) * w.z                                \
       + fmaxf(bfhi((qq).y) + p2.w, 0.f) * w.w;                               \
  }
#define EID(r) (((r).x >> 16) | (((r).y & 0xFFFFu) << 16))
  for (; i + 8 <= end; i += 8) {
    uint2 r[8];
#pragma unroll
    for (int u = 0; u < 8; ++u) r[u] = recs[i + u];
    uint2 q[8];
#pragma unroll
    for (int u = 0; u < 8; ++u)
      q[u] = *(const uint2*)(P1bf + (size_t)(r[u].x & 0xFFFFu) * DD + lane * 4);
    float v[8];
#pragma unroll
    for (int u = 0; u < 8; ++u) EDGEV(v[u], q[u])
#pragma unroll
    for (int m = 16; m >= 1; m >>= 1) {
#pragma unroll
      for (int u = 0; u < 8; ++u) v[u] += __shfl_xor(v[u], m, 64);
    }
    if (lane == 0) {
#pragma unroll
      for (int u = 0; u < 8; ++u) out[EID(r[u])] = v[u] + bb;
    }
  }
  for (; i + 4 <= end; i += 4) {
    uint2 r[4];
#pragma unroll
    for (int u = 0; u < 4; ++u) r[u] = recs[i + u];
    uint2 q[4];
#pragma unroll
    for (int u = 0; u < 4; ++u)
      q[u] = *(const uint2*)(P1bf + (size_t)(r[u].x & 0xFFFFu) * DD + lane * 4);
    float v[4];
#pragma unroll
    for (int u = 0; u < 4; ++u) EDGEV(v[u], q[u])
#pragma unroll
    for (int m = 16; m >= 1; m >>= 1) {
#pragma unroll
      for (int u = 0; u < 4; ++u) v[u] += __shfl_xor(v[u], m, 64);
    }
    if (lane == 0) {
#pragma unroll
      for (int u = 0; u < 4; ++u) out[EID(r[u])] = v[u] + bb;
    }
  }
  for (; i < end; ++i) {
    const uint2 r0 = recs[i];
    const uint2 q0 = *(const uint2*)(P1bf + (size_t)(r0.x & 0xFFFFu) * DD + lane * 4);
    float v;
    EDGEV(v, q0)
#pragma unroll
    for (int m = 16; m >= 1; m >>= 1) v += __shfl_xor(v, m, 64);
    if (lane == 0) out[EID(r0)] = v + bb;
  }
#undef EDGEV
#undef EID
}

// ---------------------------------------------------------------- launch
extern "C" void kernel_launch(void* const* d_in, const int* in_sizes, int n_in,
                              void* d_out, int out_size, void* d_ws, size_t ws_size,
                              hipStream_t stream) {
  const float* x_in = (const float*)d_in[0];
  const float* ea   = (const float*)d_in[1];
  const int*   ei   = (const int*)d_in[2];   // integer inputs arrive as int32
  const float* Wl1 = (const float*)d_in[3];
  const float* bl1 = (const float*)d_in[4];
  const float* Wl2 = (const float*)d_in[5];
  const float* bl2 = (const float*)d_in[6];
  const float* We  = (const float*)d_in[7];
  const float* be  = (const float*)d_in[8];
  const float* Wp1 = (const float*)d_in[9];
  const float* bp1 = (const float*)d_in[10];
  const float* Wp2 = (const float*)d_in[11];
  const float* bp2 = (const float*)d_in[12];
  const int* src = ei;
  const int* dst = ei + NE;

  // workspace layout (~75 MB)
  float* bufA   = (float*)d_ws;                    // NN*DD f32 region (used as bf16)
  float* bufB   = bufA + (size_t)NN * DD;          // NN*DD f32 region (used as bf16)
  int*   cnt    = (int*)(bufB + (size_t)NN * DD);  // NN
  int*   offs   = cnt + NN;                        // NN+1
  int*   rank   = offs + NN + 1;                   // NE
  uint2* recs   = (uint2*)(((uintptr_t)(rank + NE) + 15) & ~(uintptr_t)15); // NE x 8B
  unsigned short* WTh = (unsigned short*)(recs + NE);   // 8*16384 bf16
  unsigned short* WTl = WTh + 8 * 16384;                // 8*16384 bf16
  unsigned short* xbf = WTl + 8 * 16384;                // NN*DD bf16 (x0..x3)
  unsigned short* agg = (unsigned short*)bufA;          // NN*DD bf16 (agg out / P1bf)
  unsigned short* p2b = (unsigned short*)bufB;          // NN*DD bf16 (P2bf)

  // fused prologue + CSR build (per-launch, deterministic)
  prologue<<<(NN * DD / 2 + 255) / 256, 256, 0, stream>>>(
      Wl1, Wl2, Wp1, WTh, WTl, (const float2*)x_in, (unsigned*)xbf, cnt);
  hist_rank<<<NE / 256, 256, 0, stream>>>(dst, cnt, rank);
  scan_nodes<<<1, 1024, 0, stream>>>(cnt, offs);
  csr_fill<<<NE / 256, 256, 0, stream>>>(src, dst, ea, offs, rank, recs);

  const int GB = 1024;            // gemm grid: ~3 chunks/block
  const int AB = (NN + 7) / 8;    // 6250 blocks: 32-lane slot/node (max TLP)
#define WH(g) (WTh + (size_t)(g) * 16384)
#define WL(g) (WTl + (size_t)(g) * 16384)

  // L0: agg(xbf=x0)->agg(bf16); mlp agg -> xbf (x1)
  aggregate<<<AB, 256, 0, stream>>>(
      xbf, offs, recs, (const float4*)We, (const float4*)be, (unsigned*)agg);
  fused_mlp<<<GB, 256, 0, stream>>>(
      agg, WH(0), WL(0), WH(3), WL(3), bl1, bl2, xbf);
  // L1
  aggregate<<<AB, 256, 0, stream>>>(
      xbf, offs, recs, (const float4*)(We + DD), (const float4*)(be + DD), (unsigned*)agg);
  fused_mlp<<<GB, 256, 0, stream>>>(
      agg, WH(1), WL(1), WH(4), WL(4), bl1 + DD, bl2 + DD, xbf);
  // L2
  aggregate<<<AB, 256, 0, stream>>>(
      xbf, offs, recs, (const float4*)(We + 2 * DD), (const float4*)(be + 2 * DD), (unsigned*)agg);
  fused_mlp<<<GB, 256, 0, stream>>>(
      agg, WH(2), WL(2), WH(5), WL(5), bl1 + 2 * DD, bl2 + 2 * DD, xbf);
  // predictor: x3 = xbf.  P1bf -> agg (bufA), P2bf -> p2b (bufB).
  gemm_pred2<<<GB, 256, 0, stream>>>(xbf, WH(6), WL(6), WH(7), WL(7), bp1,
                                     agg, p2b);
  edge_out<<<AB, 256, 0, stream>>>(
      agg, p2b, offs, recs, (const float4*)Wp2, bp2, (float*)d_out);
}